// Round 4
// baseline (127.476 us; speedup 1.0000x reference)
//
#include <hip/hip_runtime.h>
#include <math.h>

#define LN2F 0.69314718055994530942f

// ws float offsets
#define WS_PL    0     // 240 : log-softmax pwm (3,20,4)
#define WS_WV    240   // 6   : w value per (j,t)
#define WS_PJT   246   // 6   : p_{j,t}
#define WS_WPROD 252   // 8
#define WS_BASEP 260
#define WS_BASEG 261
#define WS_CNT   262   // uint completion counter
#define WS_GAMMA 272   // 8*50*3 = 1200
#define WS_ZT    1472  // 3*300

__device__ __forceinline__ float sigm(float x){ return 1.0f/(1.0f+expf(-x)); }
// mish(x) = x*tanh(softplus(x)) = x*(u-1)/(u+1), u=(1+e^x)^2 (exact identity)
__device__ __forceinline__ float mishf(float x){
    if (x >= 30.0f) return x;
    float w = expf(x);
    float u = 1.0f + w; u *= u;
    return x * (u - 1.0f) / (u + 1.0f);
}

// ---------- kPre : 1 block x 64 — scalar prelude, once ----------
__global__ __launch_bounds__(64) void kPre(
    const float* __restrict__ pwm_logits,
    const float* __restrict__ wn_W1, const float* __restrict__ wn_b1,
    const float* __restrict__ wn_W2, const float* __restrict__ wn_b2,
    const float* __restrict__ wn_W3, const float* __restrict__ wn_b3,
    float* __restrict__ ws)
{
    __shared__ float h1[16], h2[16];
    __shared__ float wlp6[6], pjt6[6], bin6[6];
    int tid=threadIdx.x;
    float C4=lgammaf(0.8f)-4.0f*lgammaf(0.2f);
    float part=0.0f;
    if(tid<60){
        const float* l=pwm_logits+tid*4;
        float m=fmaxf(fmaxf(l[0],l[1]),fmaxf(l[2],l[3]));
        float se=expf(l[0]-m)+expf(l[1]-m)+expf(l[2]-m)+expf(l[3]-m);
        float ls=logf(se);
        float d=0.0f;
        for(int c=0;c<4;c++){ float v=l[c]-m-ls; ws[WS_PL+tid*4+c]=v; d+=v; }
        part=fminf(3.0f,-0.8f*d+C4);
    }
    for(int off=32;off>0;off>>=1) part += __shfl_down(part,off);   // lane0: dirsum
    if(tid<16) h1[tid]=mishf(wn_W1[tid]+wn_b1[tid]);
    __syncthreads();
    if(tid<16){
        float a=wn_b2[tid];
        for(int i=0;i<16;i++) a+=h1[i]*wn_W2[i*16+tid];
        h2[tid]=mishf(a);
    }
    __syncthreads();
    if(tid<6){
        int j=tid>>1;
        float a=wn_b3[j];
        for(int i=0;i<16;i++) a+=h2[i]*wn_W3[i*3+j];
        float mean=sigm(a)*15.0f+5.0f;
        float wv=(tid&1)?ceilf(mean):floorf(mean);
        float up=(wv>=20.0f)?1.0f:sigm((wv+0.5f-mean)*20.0f);
        float lo=(wv<=5.0f)?0.0f:sigm((wv-0.5f-mean)*20.0f);
        float wl=logf(up-lo+1e-12f);
        wlp6[tid]=wl; pjt6[tid]=expf(wl);
        bin6[tid]=lgammaf(16.0f)-lgammaf(wv+1.0f)-lgammaf(16.0f-wv)-15.0f*LN2F;
        ws[WS_WV+tid]=wv; ws[WS_PJT+tid]=pjt6[tid];
    }
    __syncthreads();
    if(tid==0){
        float bp=part, bg=0.0f;
        for(int i=0;i<8;i++){
            int b0=(i>>2)&1,b1=(i>>1)&1,b2=i&1;
            float wp=pjt6[b0]*pjt6[2+b1]*pjt6[4+b2];
            ws[WS_WPROD+i]=wp;
            bp+=wp*(bin6[b0]+bin6[2+b1]+bin6[4+b2]);
            bg+=wp*(wlp6[b0]+wlp6[2+b1]+wlp6[4+b2]);
        }
        ws[WS_BASEP]=bp; ws[WS_BASEG]=bg;
        ((unsigned int*)ws)[WS_CNT]=0u;
    }
}

// ---------- kAll : grid(700) x 256 — all tasks + last-block finalize ----------
__global__ __launch_bounds__(256) void kAll(
    const float* __restrict__ gc1W, const float* __restrict__ gc1b,
    const float* __restrict__ gc2W, const float* __restrict__ gc2b,
    const float* __restrict__ gl1W, const float* __restrict__ gl1b,
    const float* __restrict__ gl2W, const float* __restrict__ gl2b,
    const float* __restrict__ zc1W, const float* __restrict__ zc1b,
    const float* __restrict__ zc2W, const float* __restrict__ zc2b,
    const float* __restrict__ zclsW, const float* __restrict__ zclsb,
    const float* __restrict__ zdelW, const float* __restrict__ zdelb,
    const int* __restrict__ X, float* __restrict__ ws, float* __restrict__ out)
{
    int tid=threadIdx.x, bid=blockIdx.x;
    bool isC = bid<400;
    int iw=0, b, It=0, I=0;
    if(isC){ iw=bid&7; b=bid>>3; }
    else   { int idx=bid-400; It=idx%6; b=idx/6; I=It>>1; }

    __shared__ float pl[240];
    __shared__ int   xs[100];
    __shared__ float wv6s[6], pjt6s[6], wpr8s[8], base2s[2];
    __shared__ float ybuf[3][100];
    __shared__ float w1buf[240];
    __shared__ float zw2[640];
    __shared__ float hp[16][48];
    __shared__ float c2o[8][44];
    __shared__ float zz[176];
    __shared__ float pcl[72], pdl[80];
    __shared__ float cls[9], del[10];
    __shared__ float g22[22], h16[16];
    __shared__ float zmS;
    __shared__ int   lastFlag;

    for(int i=tid;i<240;i+=256) pl[i]=ws[WS_PL+i];
    if(tid<100) xs[tid]=X[b*100+tid];
    if(tid>=240&&tid<246) wv6s[tid-240]=ws[WS_WV+tid-240];
    if(tid>=246&&tid<252) pjt6s[tid-246]=ws[WS_PJT+tid-246];
    if(tid>=224&&tid<232) wpr8s[tid-224]=ws[WS_WPROD+tid-224];
    if(tid>=232&&tid<234) base2s[tid-232]=ws[WS_BASEP+tid-232];
    if(isC){ for(int i=tid;i<240;i+=256) w1buf[i]=gc1W[i]; }
    else{
        for(int i=tid;i<80;i+=256)  w1buf[i]=zc1W[i];
        for(int i=tid;i<640;i+=256) zw2[i]=zc2W[i];
    }
    __syncthreads();

    // y plane(s)
    int np = isC ? 3 : 1;
    for(int idx=tid; idx<np*100; idx+=256){
        int jj=idx/100, q=idx%100;
        int j = isC ? jj : I;
        int t = isC ? ((iw>>(2-jj))&1) : (It&1);
        int w=(int)wv6s[j*2+t];
        int left=(w-1)>>1;
        float yv=0.0f;
        if(q>=left && q<=left+100-w){
            int src=q-left;
            float s=0.0f;
            const float* pj=&pl[j*80];
            for(int k=0;k<w;k++) s+=pj[k*4+xs[src+k]];
            yv=s/(float)w;
        }
        ybuf[jj][q]=yv;
    }
    __syncthreads();

    if(isC){
        for(int idx=tid; idx<768; idx+=256){
            int o=idx/48, p2=idx%48;
            const float* wr=&w1buf[o*15];
            float bo=gc1b[o], m=-1e30f;
            for(int d=0;d<2;d++){
                int p=2*p2+d;
                float acc=bo;
                for(int i=0;i<3;i++)
                    for(int k=0;k<5;k++) acc+=ybuf[i][p+k]*wr[i*5+k];
                m=fmaxf(m,mishf(acc));
            }
            hp[o][p2]=m;
        }
        __syncthreads();
        if(tid<44){
            float acc=gc2b[0];
            for(int i=0;i<16;i++)
                for(int k=0;k<5;k++) acc+=hp[i][tid+k]*gc2W[i*5+k];
            c2o[0][tid]=mishf(acc);
        }
        __syncthreads();
        if(tid<22) g22[tid]=fmaxf(c2o[0][2*tid],c2o[0][2*tid+1]);
        __syncthreads();
        if(tid<16){
            float acc=gl1b[tid];
            for(int i=0;i<22;i++) acc+=g22[i]*gl1W[i*16+tid];
            h16[tid]=mishf(acc);
        }
        __syncthreads();
        if(tid==0){
            float o3[3], m=-1e30f;
            for(int o=0;o<3;o++){
                float acc=gl2b[o];
                for(int i=0;i<16;i++) acc+=h16[i]*gl2W[i*3+o];
                o3[o]=acc; m=fmaxf(m,acc);
            }
            float se=0.0f;
            for(int o=0;o<3;o++){ o3[o]=expf(o3[o]-m); se+=o3[o]; }
            float inv=1.0f/se;
            for(int o=0;o<3;o++) ws[WS_GAMMA+(iw*50+b)*3+o]=o3[o]*inv;
        }
    } else {
        for(int idx=tid; idx<768; idx+=256){
            int o=idx/48, p2=idx%48;
            const float* wr=&w1buf[o*5];
            float bo=zc1b[o], m=-1e30f;
            for(int d=0;d<2;d++){
                int p=2*p2+d;
                float acc=bo;
                for(int k=0;k<5;k++) acc+=ybuf[0][p+k]*wr[k];
                m=fmaxf(m,mishf(acc));
            }
            hp[o][p2]=m;
        }
        __syncthreads();
        for(int idx=tid; idx<352; idx+=256){
            int o=idx/44, p=idx%44;
            float acc=zc2b[o];
            for(int i=0;i<16;i++)
                for(int k=0;k<5;k++) acc+=hp[i][p+k]*zw2[(o*16+i)*5+k];
            c2o[o][p]=mishf(acc);
        }
        __syncthreads();
        if(tid<176){
            int o=tid/22, q=tid%22;
            zz[tid]=fmaxf(c2o[o][2*q],c2o[o][2*q+1]);
        }
        __syncthreads();
        if(tid<72){                                // cls partials: 9 out x 8 chunks of 22
            int o=tid>>3, p=tid&7; int m0=p*22;
            float a=0.0f;
            for(int i2=0;i2<22;i2++) a+=zz[m0+i2]*zclsW[(m0+i2)*9+o];
            pcl[tid]=a;
        } else if(tid<152){                        // del partials: 10 out x 8 chunks
            int t2=tid-72; int n=t2>>3, p=t2&7; int m0=p*22;
            float a=0.0f;
            for(int i2=0;i2<22;i2++) a+=zz[m0+i2]*zdelW[(m0+i2)*10+n];
            pdl[t2]=a;
        }
        __syncthreads();
        if(tid<9){ float a=zclsb[tid]; for(int p=0;p<8;p++) a+=pcl[tid*8+p]; cls[tid]=a; }
        if(tid>=32&&tid<42){ int n=tid-32; float a=zdelb[n]; for(int p=0;p<8;p++) a+=pdl[n*8+p]; del[n]=sigm(a); }
        __syncthreads();
        if(tid==0){
            int ind=0; float best=cls[0];
            for(int n2=1;n2<9;n2++) if(cls[n2]>best){best=cls[n2];ind=n2;}
            ind+=1;
            zmS=((float)ind+del[ind])*7.9f;        // gap=(99-20)/10
        }
        __syncthreads();
        if(tid<64){
            float Zm=zmS; int wI=(int)wv6s[It];
            int s=tid>>5, k=tid&31;
            float zf = s?ceilf(Zm):floorf(Zm);
            float up=(zf>=99.0f)?1.0f:sigm((zf+0.5f-Zm)*20.0f);
            float lo=(zf<=0.0f)?0.0f:sigm((zf-0.5f-Zm)*20.0f);
            float zlp=logf(up-lo+1e-12f);
            float zp=expf(zlp);
            float bin=lgammaf(80.0f)-lgammaf(zf+1.0f)-lgammaf(80.0f-zf)-79.0f*LN2F;
            int zi=(int)zf;
            const float* pI=&pl[I*80];
            float lpv=0.0f;
            if(k<wI){ int p=zi+k; if(p>99)p=99; lpv=pI[k*4+xs[p]]; }
            for(int off=16;off>0;off>>=1) lpv += __shfl_down(lpv,off);
            float zp1=__shfl(zp,32), zlp1=__shfl(zlp,32), bin1=__shfl(bin,32), lpv1=__shfl(lpv,32);
            if(tid==0){
                ws[WS_ZT+    It*50+b]=zp*bin +zp1*bin1;
                ws[WS_ZT+300+It*50+b]=zp*zlp +zp1*zlp1;
                ws[WS_ZT+600+It*50+b]=zp*lpv +zp1*lpv1;
            }
        }
    }

    // ---- completion + last-block finalize ----
    __syncthreads();
    if(tid==0){
        __threadfence();
        unsigned int old=atomicAdd((unsigned int*)ws+WS_CNT,1u);
        lastFlag=(old==699u)?1:0;
    }
    __syncthreads();
    if(!lastFlag) return;
    __threadfence();

    float* red=&hp[0][0];                          // reuse 768 floats as 3x256 scratch
    float C3=lgammaf(0.6f)-3.0f*lgammaf(0.2f);
    float pp=0.0f, pg=0.0f, px=0.0f;
    for(int idx=tid; idx<400; idx+=256){           // gamma Dirichlet prior
        int iw2=idx/50, b2=idx%50;
        const float* g=&ws[WS_GAMMA+(iw2*50+b2)*3];
        float lp=-0.8f*(logf(g[0])+logf(g[1])+logf(g[2]))+C3;
        pp+=wpr8s[iw2]*fminf(3.0f,lp);
    }
    for(int idx=tid; idx<300; idx+=256){           // z contraction
        int It2=idx/50, b2=idx%50;
        int I2=It2>>1, t2=It2&1;
        float gs=0.0f;
        for(int iw2=0;iw2<8;iw2++)
            if(((iw2>>(2-I2))&1)==t2) gs+=ws[WS_GAMMA+(iw2*50+b2)*3+I2];
        float G=pjt6s[It2]*gs;
        pp+=G*ws[WS_ZT+idx];
        pg+=G*ws[WS_ZT+300+idx];
        px+=G*ws[WS_ZT+600+idx];
    }
    red[tid]=pp; red[256+tid]=pg; red[512+tid]=px;
    __syncthreads();
    for(int s2=128;s2>0;s2>>=1){
        if(tid<s2){
            red[tid]+=red[tid+s2];
            red[256+tid]+=red[256+tid+s2];
            red[512+tid]+=red[512+tid+s2];
        }
        __syncthreads();
    }
    if(tid==0){
        float log_prior=base2s[0]+red[0];
        float log_guide=base2s[1]+red[256];
        out[0] = -red[512] - log_prior + log_guide;
    }
}

extern "C" void kernel_launch(void* const* d_in, const int* in_sizes, int n_in,
                              void* d_out, int out_size, void* d_ws, size_t ws_size,
                              hipStream_t stream)
{
    const float* pwm_logits=(const float*)d_in[0];
    const float* wn_W1 =(const float*)d_in[1];
    const float* wn_b1 =(const float*)d_in[2];
    const float* wn_W2 =(const float*)d_in[3];
    const float* wn_b2 =(const float*)d_in[4];
    const float* wn_W3 =(const float*)d_in[5];
    const float* wn_b3 =(const float*)d_in[6];
    const float* gn_c1W=(const float*)d_in[7];
    const float* gn_c1b=(const float*)d_in[8];
    const float* gn_c2W=(const float*)d_in[9];
    const float* gn_c2b=(const float*)d_in[10];
    const float* gn_l1W=(const float*)d_in[11];
    const float* gn_l1b=(const float*)d_in[12];
    const float* gn_l2W=(const float*)d_in[13];
    const float* gn_l2b=(const float*)d_in[14];
    const float* zn_c1W=(const float*)d_in[15];
    const float* zn_c1b=(const float*)d_in[16];
    const float* zn_c2W=(const float*)d_in[17];
    const float* zn_c2b=(const float*)d_in[18];
    const float* zn_clsW=(const float*)d_in[19];
    const float* zn_clsb=(const float*)d_in[20];
    const float* zn_delW=(const float*)d_in[21];
    const float* zn_delb=(const float*)d_in[22];
    const int*   X     =(const int*)d_in[23];
    float* ws =(float*)d_ws;
    float* out=(float*)d_out;

    hipLaunchKernelGGL(kPre, dim3(1),   dim3(64),  0, stream,
                       pwm_logits, wn_W1, wn_b1, wn_W2, wn_b2, wn_W3, wn_b3, ws);
    hipLaunchKernelGGL(kAll, dim3(700), dim3(256), 0, stream,
                       gn_c1W, gn_c1b, gn_c2W, gn_c2b, gn_l1W, gn_l1b, gn_l2W, gn_l2b,
                       zn_c1W, zn_c1b, zn_c2W, zn_c2b, zn_clsW, zn_clsb, zn_delW, zn_delb,
                       X, ws, out);
}